// Round 8
// baseline (28426.862 us; speedup 1.0000x reference)
//
#include <hip/hip_runtime.h>
#include <hip/hip_bf16.h>

typedef __attribute__((ext_vector_type(8))) short bh8;     // 8 bf16 (4 VGPRs)
typedef __attribute__((ext_vector_type(4))) float fx4;     // MFMA C/D
typedef __attribute__((ext_vector_type(4))) unsigned int ux4;
typedef unsigned int u32;
typedef unsigned long long u64;

#define S_LEN 2048
#define OUTBASE 16777216   // 8*2048*1024

__device__ __forceinline__ unsigned short f2bf(float f) {
  __hip_bfloat16 h = __float2bfloat16(f);
  unsigned short u; __builtin_memcpy(&u, &h, 2); return u;
}
__device__ __forceinline__ float bf2f(unsigned short u) {
  __hip_bfloat16 h; __builtin_memcpy(&h, &u, 2); return __bfloat162float(h);
}

// ---------------- prep: transpose + bf16-convert Wx for the big GEMM ----------------
__global__ __launch_bounds__(256) void prep_w(
    const float* __restrict__ Wi, const float* __restrict__ Wf,
    const float* __restrict__ Wg, const float* __restrict__ Wo,
    __hip_bfloat16* __restrict__ WxT) {
  __shared__ float tile[32][33];
  const int z = blockIdx.z;
  const float* src = (z==0)?Wi:(z==1)?Wf:(z==2)?Wg:Wo;
  const int kbase = blockIdx.y * 32, cbase = blockIdx.x * 32;
  const int tx = threadIdx.x, ty = threadIdx.y;
#pragma unroll
  for (int rr = 0; rr < 4; ++rr)
    tile[ty*4+rr][tx] = src[(size_t)(kbase + ty*4+rr)*1024 + cbase + tx];
  __syncthreads();
#pragma unroll
  for (int rr = 0; rr < 4; ++rr) {
    int c = cbase + ty*4+rr;
    int k = kbase + tx;
    WxT[(size_t)(z*1024 + c)*1024 + k] = __float2bfloat16(tile[tx][ty*4+rr]);
  }
}

// ---------------- prep: gate-weight MFMA B-fragments (Wh part, rows 1024..2047) ----
__global__ __launch_bounds__(128) void prep_gfrag(
    const float* __restrict__ Wi, const float* __restrict__ Wf,
    const float* __restrict__ Wg, const float* __restrict__ Wo,
    bh8* __restrict__ gfrag) {
  const int bx = blockIdx.x;                 // 4096 = 32 jb * 4 g * 32 ks
  const int jb = bx >> 7, g = (bx >> 5) & 3, ks = bx & 31;
  const int tid = threadIdx.x, lane = tid & 63, ct = tid >> 6;
  const float* W = (g==0)?Wi:(g==1)?Wf:(g==2)?Wg:Wo;
  const int col = jb*32 + ct*16 + (lane & 15);
  const int kb = ks*32 + ((lane >> 4) & 3)*8;
  unsigned short o[8];
#pragma unroll
  for (int i = 0; i < 8; ++i)
    o[i] = f2bf(W[(size_t)(1024 + kb + i)*1024 + col]);
  bh8 v; __builtin_memcpy(&v, o, 16);
  gfrag[((size_t)(jb*4 + g)*64 + ks*2 + ct)*64 + lane] = v;
}

// ---------------- prep: Weg MFMA B-fragments ----------------
__global__ __launch_bounds__(128) void prep_wegfrag(
    const float* __restrict__ Weg, bh8* __restrict__ wegfrag) {
  const int bx = blockIdx.x;                 // 1024 = 32 jb * 4 wv * 8 ks
  const int jb = bx >> 5, wv = (bx >> 3) & 3, ks = bx & 7;
  const int tid = threadIdx.x, lane = tid & 63, ct = tid >> 6;
  const int col = jb*32 + ct*16 + (lane & 15);
  const int kb = wv*256 + ks*32 + ((lane >> 4) & 3)*8;
  unsigned short o[8];
#pragma unroll
  for (int i = 0; i < 8; ++i)
    o[i] = f2bf(Weg[(size_t)(kb + i)*1024 + col]);
  bh8 v; __builtin_memcpy(&v, o, 16);
  wegfrag[((size_t)(jb*4 + wv)*16 + ks*2 + ct)*64 + lane] = v;
}

// ---------------- init: zero tag buffers + team counters; bias concat ----------------
__global__ __launch_bounds__(256) void init_k(
    u32* h_tag, u32* g_tag, int* teamcnt,
    const float* __restrict__ bi, const float* __restrict__ bfv,
    const float* __restrict__ bg, const float* __restrict__ bo,
    float* __restrict__ bcat) {
  int t = blockIdx.x * 256 + threadIdx.x;
  if (t < 8192) { h_tag[t] = 0u; g_tag[t] = 0u; }   // value bf16(0), tag 0
  if (t < 32) teamcnt[t] = 0;
  if (t < 4096) {
    float v = (t < 1024) ? bi[t] : (t < 2048) ? bfv[t-1024]
            : (t < 3072) ? bg[t-2048] : bo[t-3072];
    bcat[t] = v;
  }
}

// ---------------- convert x to bf16 ----------------
__global__ __launch_bounds__(256) void conv_x(const float* __restrict__ x,
                                              __hip_bfloat16* __restrict__ xbf) {
  size_t i = ((size_t)blockIdx.x * 256 + threadIdx.x) * 8;
  fx4 a = *reinterpret_cast<const fx4*>(x + i);
  fx4 b = *reinterpret_cast<const fx4*>(x + i + 4);
  unsigned short o[8];
#pragma unroll
  for (int u = 0; u < 4; ++u) { o[u] = f2bf(a[u]); o[4+u] = f2bf(b[u]); }
  bh8 v; __builtin_memcpy(&v, o, 16);
  *reinterpret_cast<bh8*>(xbf + i) = v;
}

// ---------------- phase-1 GEMM: XG[s*8+b][c] = x @ Wx + bias (bf16) ----------------
__global__ __launch_bounds__(256) void gemm_x(
    const __hip_bfloat16* __restrict__ xbf,
    const __hip_bfloat16* __restrict__ WxT,
    const float* __restrict__ bcat,
    __hip_bfloat16* __restrict__ XG) {
  __shared__ bh8 ldsv[2048];                 // 32 KB
  char* lds = reinterpret_cast<char*>(ldsv);
  const int tid = threadIdx.x;
  const int bn = blockIdx.x, bm = blockIdx.y;
  const int lane = tid & 63, wid = tid >> 6;
  const int wr = wid >> 1, wc = wid & 1;
  fx4 acc[4][4] = {};
  for (int kb = 0; kb < 16; ++kb) {
    __syncthreads();
#pragma unroll
    for (int c = 0; c < 4; ++c) {
      int cid = tid + 256 * c;
      int r = cid >> 3, kc = cid & 7;
      bh8 va = *reinterpret_cast<const bh8*>(xbf + (size_t)(bm*128 + r)*1024 + kb*64 + kc*8);
      int off = (r*128 + kc*16) ^ ((r & 7) << 4);
      *reinterpret_cast<bh8*>(lds + off) = va;
      bh8 vb = *reinterpret_cast<const bh8*>(WxT + (size_t)(bn*128 + r)*1024 + kb*64 + kc*8);
      *reinterpret_cast<bh8*>(lds + 16384 + off) = vb;
    }
    __syncthreads();
#pragma unroll
    for (int ks = 0; ks < 2; ++ks) {
      bh8 af[4], bfr[4];
      int ac = ks*64 + (lane >> 4) * 16;
#pragma unroll
      for (int i = 0; i < 4; ++i) {
        int ar = wr*64 + i*16 + (lane & 15);
        af[i] = *reinterpret_cast<const bh8*>(lds + ((ar*128 + ac) ^ ((ar & 7) << 4)));
        int br = wc*64 + i*16 + (lane & 15);
        bfr[i] = *reinterpret_cast<const bh8*>(lds + 16384 + ((br*128 + ac) ^ ((br & 7) << 4)));
      }
#pragma unroll
      for (int i = 0; i < 4; ++i)
#pragma unroll
        for (int jn = 0; jn < 4; ++jn)
          acc[i][jn] = __builtin_amdgcn_mfma_f32_16x16x32_bf16(af[i], bfr[jn], acc[i][jn], 0, 0, 0);
    }
  }
#pragma unroll
  for (int i = 0; i < 4; ++i) {
    int rbase = bm*128 + wr*64 + i*16 + (lane >> 4) * 4;
#pragma unroll
    for (int jn = 0; jn < 4; ++jn) {
      int col = bn*128 + wc*64 + jn*16 + (lane & 15);
      float bias = bcat[col];
#pragma unroll
      for (int jj = 0; jj < 4; ++jj) {
        int r = rbase + jj;
        int b = r >> 11, s = r & 2047;
        XG[(size_t)(s*8 + b)*4096 + col] = __float2bfloat16(acc[i][jn][jj] + bias);
      }
    }
  }
}

// ---------------- batched 2-chunk tagged poll (L2-local; rare L3 fallback) ----------
__device__ __forceinline__ void poll2(const u32* p, u32 etag, int rnd0,
                                      u64& o0, u64& o1) {
  int rnd = rnd0 & 15;
  while (true) {
    ux4 v0, v1;
    if ((rnd & 15) != 15) {
      asm volatile("global_load_dwordx4 %0, %2, off sc0\n\t"
                   "global_load_dwordx4 %1, %2, off offset:16 sc0\n\t"
                   "s_waitcnt vmcnt(0)"
                   : "=&v"(v0), "=&v"(v1) : "v"(p) : "memory");
    } else {
      asm volatile("global_load_dwordx4 %0, %2, off sc0 sc1\n\t"
                   "global_load_dwordx4 %1, %2, off offset:16 sc0 sc1\n\t"
                   "s_waitcnt vmcnt(0)"
                   : "=&v"(v0), "=&v"(v1) : "v"(p) : "memory");
    }
    ++rnd;
    u32 bad = ((v0.x ^ etag) | (v0.y ^ etag) | (v0.z ^ etag) | (v0.w ^ etag)
             | (v1.x ^ etag) | (v1.y ^ etag) | (v1.z ^ etag) | (v1.w ^ etag)) & 0xffffu;
    if (!bad) {
      o0 = (u64)((v0.x >> 16) | (v0.y & 0xffff0000u))
         | ((u64)((v0.z >> 16) | (v0.w & 0xffff0000u)) << 32);
      o1 = (u64)((v1.x >> 16) | (v1.y & 0xffff0000u))
         | ((u64)((v1.z >> 16) | (v1.w & 0xffff0000u)) << 32);
      return;
    }
  }
}

// ---------------- persistent recurrence: batch-per-XCD, resident weights ----------
struct __align__(16) RecurLds {
  bh8 gwlds[32][64];          // 32 KB: [w*8 + gate*2 + ct][lane], k8 = 0 frags
  u64 hstage[256];            // 2 KB: h vector, 4 bf16 per entry
  u64 gstage[256];            // 2 KB
  float pg[4][32];            // g-gate K-partials
  float actp[4][3][32];       // i/f/o K-partials
  float gact[32];             // activated g
  unsigned short xg[2][128];  // XG slice double-buffer [gate*32+col]
  int ids[2];
};

__global__ void __launch_bounds__(256, 1) __attribute__((amdgpu_waves_per_eu(1, 1)))
recur(const bh8* __restrict__ gfrag, const bh8* __restrict__ wegfrag,
      const __hip_bfloat16* __restrict__ XG, const float* __restrict__ beg,
      u32* h_tag, u32* g_tag, int* teamcnt, float* d_out) {
  __shared__ RecurLds L;
  const int tid = threadIdx.x;
  const int w = tid >> 6, lane = tid & 63, rgrp = lane >> 4;

  // rendezvous: team = physical XCD, role jb = claim order within team
  if (tid == 0) {
    u32 xid;
    asm volatile("s_getreg_b32 %0, hwreg(HW_REG_XCC_ID)" : "=s"(xid));
    L.ids[0] = (int)(xid & 7u);
    L.ids[1] = atomicAdd(&teamcnt[xid & 7u], 1) & 31;
  }
  __syncthreads();
  const int b = L.ids[0], jb = L.ids[1];     // batch b, owns h-cols [jb*32, jb*32+32)

  // k8=0 gate frags -> LDS; k8=1..7 -> VGPR (statically indexed, 56 frags)
#pragma unroll
  for (int g = 0; g < 4; ++g)
#pragma unroll
    for (int ct = 0; ct < 2; ++ct)
      L.gwlds[w*8 + g*2 + ct][lane] =
          gfrag[((size_t)(jb*4 + g)*64 + (w*8 + 0)*2 + ct)*64 + lane];
  bh8 greg[56];
#pragma unroll
  for (int g = 0; g < 4; ++g)
#pragma unroll
    for (int k8 = 1; k8 < 8; ++k8)
#pragma unroll
      for (int ct = 0; ct < 2; ++ct)
        greg[(g*7 + (k8-1))*2 + ct] =
            gfrag[((size_t)(jb*4 + g)*64 + (w*8 + k8)*2 + ct)*64 + lane];

  float begv = 0.f, c_st = 0.f, n_st = 0.f;
  float i_v = 0.f, f_v = 0.f, o_v = 0.f, c_new = 0.f;
  if (w < 2 && lane < 16) begv = beg[jb*32 + w*16 + lane];
  if (tid < 32) {  // stage XG[0]  (layout gate*32+col)
    int gate = tid >> 3, ch = tid & 7;
    u64 v = *reinterpret_cast<const u64*>(
        &XG[((size_t)b)*4096 + gate*1024 + jb*32 + ch*4]);
    reinterpret_cast<u64*>(&L.xg[0][0])[tid] = v;
  }
  __syncthreads();

#pragma unroll 1
  for (int t = 0; t < S_LEN; ++t) {
    // ---- waves 2,3: poll h(t) into hstage ----
    if (w >= 2) {
      int idx = tid - 128;
      u64 o0, o1;
      poll2(h_tag + b*1024 + idx*8, (u32)t, jb + t, o0, o1);
      L.hstage[idx*2] = o0; L.hstage[idx*2 + 1] = o1;
    }
    __syncthreads();                         // B1: hstage ready
    u64 xgv = 0;
    if (w == 2 && lane < 32 && t < S_LEN - 1) {  // XG prefetch issue (consumed post-B2)
      int gate = lane >> 3, ch = lane & 7;
      xgv = *reinterpret_cast<const u64*>(
          &XG[((size_t)(t+1)*8 + b)*4096 + gate*1024 + jb*32 + ch*4]);
    }
    // A-fragments (shared across all 4 gates)
    bh8 af[8];
#pragma unroll
    for (int k8 = 0; k8 < 8; ++k8)
      af[k8] = *reinterpret_cast<const bh8*>(
          reinterpret_cast<const char*>(L.hstage) + w*512 + k8*64 + rgrp*16);
    // ---- gate g FIRST (K-split over 4 waves) ----
    fx4 ag[2] = {{0,0,0,0},{0,0,0,0}};
#pragma unroll
    for (int k8 = 0; k8 < 8; ++k8)
#pragma unroll
      for (int ct = 0; ct < 2; ++ct) {
        bh8 bf = (k8 == 0) ? L.gwlds[w*8 + 2*2 + ct][lane]
                           : greg[(2*7 + (k8-1))*2 + ct];
        ag[ct] = __builtin_amdgcn_mfma_f32_16x16x32_bf16(af[k8], bf, ag[ct], 0, 0, 0);
      }
    if (lane < 16) { L.pg[w][lane] = ag[0][0]; L.pg[w][16 + lane] = ag[1][0]; }
    __syncthreads();                         // Bg: g partials ready
    if (w == 0 && lane < 16) {               // early g publish (other waves continue)
#pragma unroll
      for (int hh = 0; hh < 2; ++hh) {
        int c = hh*16 + lane;
        float s = L.pg[0][c] + L.pg[1][c] + L.pg[2][c] + L.pg[3][c]
                + bf2f(L.xg[t & 1][64 + c]);
        float gv = tanhf(s);
        L.gact[c] = gv;
        __hip_atomic_store(&g_tag[b*1024 + jb*32 + c],
                           ((u32)f2bf(gv) << 16) | (u32)(t + 1),
                           __ATOMIC_RELAXED, __HIP_MEMORY_SCOPE_AGENT);
      }
    }
    // ---- gates i,f,o (overlap the g-visibility window) ----
    fx4 aifo[3][2] = {};
#pragma unroll
    for (int gi = 0; gi < 3; ++gi) {
      const int g = (gi == 2) ? 3 : gi;
#pragma unroll
      for (int k8 = 0; k8 < 8; ++k8)
#pragma unroll
        for (int ct = 0; ct < 2; ++ct) {
          bh8 bf = (k8 == 0) ? L.gwlds[w*8 + g*2 + ct][lane]
                             : greg[(g*7 + (k8-1))*2 + ct];
          aifo[gi][ct] = __builtin_amdgcn_mfma_f32_16x16x32_bf16(af[k8], bf, aifo[gi][ct], 0, 0, 0);
        }
    }
    if (lane < 16) {
#pragma unroll
      for (int gi = 0; gi < 3; ++gi) {
        L.actp[w][gi][lane] = aifo[gi][0][0];
        L.actp[w][gi][16 + lane] = aifo[gi][1][0];
      }
    }
    __syncthreads();                         // B2: i/f/o partials ready
    if (w < 2 && lane < 16) {                // state update on owner lanes
      const int c = w*16 + lane;
      const unsigned short* xga = &L.xg[t & 1][0];
      float pi = L.actp[0][0][c] + L.actp[1][0][c] + L.actp[2][0][c] + L.actp[3][0][c] + bf2f(xga[c]);
      float pf = L.actp[0][1][c] + L.actp[1][1][c] + L.actp[2][1][c] + L.actp[3][1][c] + bf2f(xga[32 + c]);
      float po = L.actp[0][2][c] + L.actp[1][2][c] + L.actp[2][2][c] + L.actp[3][2][c] + bf2f(xga[96 + c]);
      i_v = 1.f / (1.f + expf(-pi));
      f_v = 1.f / (1.f + expf(-pf));
      o_v = 1.f / (1.f + expf(-po));
      c_new = f_v * c_st + i_v * L.gact[c]; c_st = c_new;
    }
    if (w == 2 && lane < 32 && t < S_LEN - 1)   // land XG prefetch
      reinterpret_cast<u64*>(&L.xg[(t+1) & 1][0])[lane] = xgv;
    if (w < 2) {                             // waves 0,1: poll g(t) into gstage
      u64 o0, o1;
      poll2(g_tag + b*1024 + tid*8, (u32)(t + 1), jb + t + 7, o0, o1);
      L.gstage[tid*2] = o0; L.gstage[tid*2 + 1] = o1;
    }
    __syncthreads();                         // B3: gstage ready
    if (w < 2) {
      // ---- phase B: wave w covers cols [w*16, w*16+16), full K ----
      fx4 eb[4] = {};
#pragma unroll
      for (int q = 0; q < 32; ++q) {
        bh8 afb = *reinterpret_cast<const bh8*>(
            reinterpret_cast<const char*>(L.gstage) + q*64 + rgrp*16);
        bh8 wb = wegfrag[((size_t)(jb*4 + (q >> 3))*16 + (q & 7)*2 + w)*64 + lane];
        eb[q & 3] = __builtin_amdgcn_mfma_f32_16x16x32_bf16(afb, wb, eb[q & 3], 0, 0, 0);
      }
      if (lane < 16) {
        const int c = w*16 + lane;
        float e = eb[0][0] + eb[1][0] + eb[2][0] + eb[3][0];
        float ex = expf(e + begv);
        float n_new = f_v * n_st + i_v * ex; n_st = n_new;
        float h_new = o_v * (c_new / n_new);
        __hip_atomic_store(&h_tag[b*1024 + jb*32 + c],
                           ((u32)f2bf(h_new) << 16) | (u32)(t + 1),
                           __ATOMIC_RELAXED, __HIP_MEMORY_SCOPE_AGENT);
        d_out[((size_t)b*2048 + t)*1024 + jb*32 + c] = h_new;   // h history (pre-LN)
        if (t == S_LEN - 1) {
          d_out[OUTBASE +         (size_t)b*1024 + jb*32 + c] = h_new;  // h_f
          d_out[OUTBASE +  8192 + (size_t)b*1024 + jb*32 + c] = c_new;  // c_f
          d_out[OUTBASE + 16384 + (size_t)b*1024 + jb*32 + c] = n_new;  // n_f
        }
      }
    }
  }
}

// ---------------- residual + LayerNorm (in-place on d_out) ----------------
__global__ __launch_bounds__(256) void ln_k(const float* __restrict__ x,
                                            const float* __restrict__ gamma,
                                            const float* __restrict__ beta,
                                            float* __restrict__ out) {
  const int r = blockIdx.x, tid = threadIdx.x;
  float* orow = out + (size_t)r * 1024;
  const float* xrow = x + (size_t)r * 1024;
  fx4 h4 = *reinterpret_cast<const fx4*>(orow + tid*4);
  fx4 x4 = *reinterpret_cast<const fx4*>(xrow + tid*4);
  fx4 y = h4 + x4;
  float s = y[0] + y[1] + y[2] + y[3];
  float s2 = y[0]*y[0] + y[1]*y[1] + y[2]*y[2] + y[3]*y[3];
#pragma unroll
  for (int m = 1; m < 64; m <<= 1) { s += __shfl_xor(s, m, 64); s2 += __shfl_xor(s2, m, 64); }
  __shared__ float ps[4], ps2[4], stats[2];
  if ((tid & 63) == 0) { ps[tid >> 6] = s; ps2[tid >> 6] = s2; }
  __syncthreads();
  if (tid == 0) {
    float t1 = ps[0] + ps[1] + ps[2] + ps[3];
    float t2 = ps2[0] + ps2[1] + ps2[2] + ps2[3];
    float mu = t1 * (1.f / 1024.f);
    float var = t2 * (1.f / 1024.f) - mu * mu;
    stats[0] = mu; stats[1] = rsqrtf(var + 1e-5f);
  }
  __syncthreads();
  float mu = stats[0], rs = stats[1];
  fx4 g4 = *reinterpret_cast<const fx4*>(gamma + tid*4);
  fx4 b4 = *reinterpret_cast<const fx4*>(beta + tid*4);
  fx4 o4;
#pragma unroll
  for (int u = 0; u < 4; ++u) o4[u] = (y[u] - mu) * rs * g4[u] + b4[u];
  *reinterpret_cast<fx4*>(orow + tid*4) = o4;
}

extern "C" void kernel_launch(void* const* d_in, const int* in_sizes, int n_in,
                              void* d_out, int out_size, void* d_ws, size_t ws_size,
                              hipStream_t stream) {
  const float* x    = (const float*)d_in[0];
  const float* Wi   = (const float*)d_in[1];
  const float* bi   = (const float*)d_in[2];
  const float* Wf   = (const float*)d_in[3];
  const float* bfv  = (const float*)d_in[4];
  const float* Wg   = (const float*)d_in[5];
  const float* bg   = (const float*)d_in[6];
  const float* Wo   = (const float*)d_in[7];
  const float* bo   = (const float*)d_in[8];
  const float* Weg  = (const float*)d_in[9];
  const float* beg  = (const float*)d_in[10];
  const float* gamma= (const float*)d_in[11];
  const float* beta = (const float*)d_in[12];
  float* out = (float*)d_out;
  char* ws = (char*)d_ws;

  __hip_bfloat16* XG   = (__hip_bfloat16*)(ws);                    // 134217728 B
  __hip_bfloat16* xbf  = (__hip_bfloat16*)(ws + 134217728ull);     //  33554432 B
  __hip_bfloat16* WxT  = (__hip_bfloat16*)(ws + 167772160ull);     //   8388608 B
  bh8* gfrag           = (bh8*)(ws + 176160768ull);                //   8388608 B
  bh8* wegfrag         = (bh8*)(ws + 184549376ull);                //   2097152 B
  float* bcat          = (float*)(ws + 186646528ull);              //     16384 B
  u32* h_tag           = (u32*)(ws + 186662912ull);                //     32768 B
  u32* g_tag           = (u32*)(ws + 186695680ull);                //     32768 B
  int* teamcnt         = (int*)(ws + 186728448ull);                //       128 B

  prep_w<<<dim3(32, 32, 4), dim3(32, 8), 0, stream>>>(Wi, Wf, Wg, Wo, WxT);
  prep_gfrag<<<dim3(4096), dim3(128), 0, stream>>>(Wi, Wf, Wg, Wo, gfrag);
  prep_wegfrag<<<dim3(1024), dim3(128), 0, stream>>>(Weg, wegfrag);
  init_k<<<dim3(64), dim3(256), 0, stream>>>(h_tag, g_tag, teamcnt, bi, bfv, bg, bo, bcat);
  conv_x<<<dim3(8192), dim3(256), 0, stream>>>(x, xbf);
  gemm_x<<<dim3(32, 128), dim3(256), 0, stream>>>(xbf, WxT, bcat, XG);
  recur<<<dim3(256), dim3(256), 0, stream>>>(gfrag, wegfrag, XG, beg, h_tag, g_tag, teamcnt, out);
  ln_k<<<dim3(16384), dim3(256), 0, stream>>>(x, gamma, beta, out);
}

// Round 9
// 8034.750 us; speedup vs baseline: 3.5380x; 3.5380x over previous
//
#include <hip/hip_runtime.h>
#include <hip/hip_bf16.h>
#include <hip/hip_fp8.h>

typedef __attribute__((ext_vector_type(8))) short bh8;     // 8 bf16 (4 VGPRs)
typedef __attribute__((ext_vector_type(4))) float fx4;     // MFMA C/D
typedef __attribute__((ext_vector_type(4))) unsigned int ux4;
typedef unsigned int u32;
typedef unsigned long long u64;

#define S_LEN 2048
#define OUTBASE 16777216   // 8*2048*1024

__device__ __forceinline__ unsigned short f2bf(float f) {
  __hip_bfloat16 h = __float2bfloat16(f);
  unsigned short u; __builtin_memcpy(&u, &h, 2); return u;
}
__device__ __forceinline__ float bf2f(unsigned short u) {
  __hip_bfloat16 h; __builtin_memcpy(&h, &u, 2); return __bfloat162float(h);
}

// ---------------- prep: transpose + bf16-convert Wx for the big GEMM ----------------
__global__ __launch_bounds__(256) void prep_w(
    const float* __restrict__ Wi, const float* __restrict__ Wf,
    const float* __restrict__ Wg, const float* __restrict__ Wo,
    __hip_bfloat16* __restrict__ WxT) {
  __shared__ float tile[32][33];
  const int z = blockIdx.z;
  const float* src = (z==0)?Wi:(z==1)?Wf:(z==2)?Wg:Wo;
  const int kbase = blockIdx.y * 32, cbase = blockIdx.x * 32;
  const int tx = threadIdx.x, ty = threadIdx.y;
#pragma unroll
  for (int rr = 0; rr < 4; ++rr)
    tile[ty*4+rr][tx] = src[(size_t)(kbase + ty*4+rr)*1024 + cbase + tx];
  __syncthreads();
#pragma unroll
  for (int rr = 0; rr < 4; ++rr) {
    int c = cbase + ty*4+rr;
    int k = kbase + tx;
    WxT[(size_t)(z*1024 + c)*1024 + k] = __float2bfloat16(tile[tx][ty*4+rr]);
  }
}

// ------------- prep: gate-weight fp8 MFMA B-frags (Wh rows 1024..2047, x16 scale) ---
// layout: gf8[jb*131072 + ((g*2+ct)*32 + k32)*512 + lane*8 + i] =
//   fp8( 16 * W_g[1024 + k32*32 + (lane>>4)*8 + i][jb*32 + ct*16 + (lane&15)] )
__global__ __launch_bounds__(128) void prep_gfrag8(
    const float* __restrict__ Wi, const float* __restrict__ Wf,
    const float* __restrict__ Wg, const float* __restrict__ Wo,
    unsigned char* __restrict__ gf8) {
  const int bx = blockIdx.x;                 // 4096 = 32 jb * 4 g * 32 k32
  const int jb = bx >> 7, g = (bx >> 5) & 3, k32 = bx & 31;
  const int tid = threadIdx.x, lane = tid & 63, ct = tid >> 6;
  const float* W = (g==0)?Wi:(g==1)?Wf:(g==2)?Wg:Wo;
  const int col = jb*32 + ct*16 + (lane & 15);
  const int kb = 1024 + k32*32 + ((lane >> 4) & 3)*8;
  unsigned char o[8];
#pragma unroll
  for (int i = 0; i < 8; ++i) {
    __hip_fp8_e4m3 q(W[(size_t)(kb + i)*1024 + col] * 16.0f);
    o[i] = q.__x;
  }
  u64 v; __builtin_memcpy(&v, o, 8);
  *reinterpret_cast<u64*>(gf8 + (size_t)jb*131072 +
                          (((g*2 + ct)*32 + k32)*512) + lane*8) = v;
}

// ---------------- prep: Weg fp8 MFMA B-fragments (x16 scale) ----------------
__global__ __launch_bounds__(128) void prep_wegfrag8(
    const float* __restrict__ Weg, unsigned char* __restrict__ wg8) {
  const int bx = blockIdx.x;                 // 1024 = 32 jb * 32 k32
  const int jb = bx >> 5, k32 = bx & 31;
  const int tid = threadIdx.x, lane = tid & 63, ct = tid >> 6;
  const int col = jb*32 + ct*16 + (lane & 15);
  const int kb = k32*32 + ((lane >> 4) & 3)*8;
  unsigned char o[8];
#pragma unroll
  for (int i = 0; i < 8; ++i) {
    __hip_fp8_e4m3 q(Weg[(size_t)(kb + i)*1024 + col] * 16.0f);
    o[i] = q.__x;
  }
  u64 v; __builtin_memcpy(&v, o, 8);
  *reinterpret_cast<u64*>(wg8 + (size_t)jb*32768 + ((k32*2 + ct)*512) + lane*8) = v;
}

// ---------------- init: zero tag buffers + team counters; bias concat ----------------
__global__ __launch_bounds__(256) void init_k(
    u32* h_tag, u32* g_tag, int* teamcnt,
    const float* __restrict__ bi, const float* __restrict__ bfv,
    const float* __restrict__ bg, const float* __restrict__ bo,
    float* __restrict__ bcat) {
  int t = blockIdx.x * 256 + threadIdx.x;
  if (t < 8192) { h_tag[t] = 0u; g_tag[t] = 0u; }   // value bf16(0), tag 0
  if (t < 32) teamcnt[t] = 0;
  if (t < 4096) {
    float v = (t < 1024) ? bi[t] : (t < 2048) ? bfv[t-1024]
            : (t < 3072) ? bg[t-2048] : bo[t-3072];
    bcat[t] = v;
  }
}

// ---------------- convert x to bf16 ----------------
__global__ __launch_bounds__(256) void conv_x(const float* __restrict__ x,
                                              __hip_bfloat16* __restrict__ xbf) {
  size_t i = ((size_t)blockIdx.x * 256 + threadIdx.x) * 8;
  fx4 a = *reinterpret_cast<const fx4*>(x + i);
  fx4 b = *reinterpret_cast<const fx4*>(x + i + 4);
  unsigned short o[8];
#pragma unroll
  for (int u = 0; u < 4; ++u) { o[u] = f2bf(a[u]); o[4+u] = f2bf(b[u]); }
  bh8 v; __builtin_memcpy(&v, o, 16);
  *reinterpret_cast<bh8*>(xbf + i) = v;
}

// ---------------- phase-1 GEMM: XG[s*8+b][c] = x @ Wx + bias (bf16) ----------------
__global__ __launch_bounds__(256) void gemm_x(
    const __hip_bfloat16* __restrict__ xbf,
    const __hip_bfloat16* __restrict__ WxT,
    const float* __restrict__ bcat,
    __hip_bfloat16* __restrict__ XG) {
  __shared__ bh8 ldsv[2048];                 // 32 KB
  char* lds = reinterpret_cast<char*>(ldsv);
  const int tid = threadIdx.x;
  const int bn = blockIdx.x, bm = blockIdx.y;
  const int lane = tid & 63, wid = tid >> 6;
  const int wr = wid >> 1, wc = wid & 1;
  fx4 acc[4][4] = {};
  for (int kb = 0; kb < 16; ++kb) {
    __syncthreads();
#pragma unroll
    for (int c = 0; c < 4; ++c) {
      int cid = tid + 256 * c;
      int r = cid >> 3, kc = cid & 7;
      bh8 va = *reinterpret_cast<const bh8*>(xbf + (size_t)(bm*128 + r)*1024 + kb*64 + kc*8);
      int off = (r*128 + kc*16) ^ ((r & 7) << 4);
      *reinterpret_cast<bh8*>(lds + off) = va;
      bh8 vb = *reinterpret_cast<const bh8*>(WxT + (size_t)(bn*128 + r)*1024 + kb*64 + kc*8);
      *reinterpret_cast<bh8*>(lds + 16384 + off) = vb;
    }
    __syncthreads();
#pragma unroll
    for (int ks = 0; ks < 2; ++ks) {
      bh8 af[4], bfr[4];
      int ac = ks*64 + (lane >> 4) * 16;
#pragma unroll
      for (int i = 0; i < 4; ++i) {
        int ar = wr*64 + i*16 + (lane & 15);
        af[i] = *reinterpret_cast<const bh8*>(lds + ((ar*128 + ac) ^ ((ar & 7) << 4)));
        int br = wc*64 + i*16 + (lane & 15);
        bfr[i] = *reinterpret_cast<const bh8*>(lds + 16384 + ((br*128 + ac) ^ ((br & 7) << 4)));
      }
#pragma unroll
      for (int i = 0; i < 4; ++i)
#pragma unroll
        for (int jn = 0; jn < 4; ++jn)
          acc[i][jn] = __builtin_amdgcn_mfma_f32_16x16x32_bf16(af[i], bfr[jn], acc[i][jn], 0, 0, 0);
    }
  }
#pragma unroll
  for (int i = 0; i < 4; ++i) {
    int rbase = bm*128 + wr*64 + i*16 + (lane >> 4) * 4;
#pragma unroll
    for (int jn = 0; jn < 4; ++jn) {
      int col = bn*128 + wc*64 + jn*16 + (lane & 15);
      float bias = bcat[col];
#pragma unroll
      for (int jj = 0; jj < 4; ++jj) {
        int r = rbase + jj;
        int b = r >> 11, s = r & 2047;
        XG[(size_t)(s*8 + b)*4096 + col] = __float2bfloat16(acc[i][jn][jj] + bias);
      }
    }
  }
}

// ---------------- XCD-local loads: sc0 = bypass L1, hit local L2 ----------------
__device__ __forceinline__ ux4 ld_sc0(const u32* p) {
  ux4 r;
  asm volatile("global_load_dwordx4 %0, %1, off sc0\n\ts_waitcnt vmcnt(0)"
               : "=v"(r) : "v"(p) : "memory");
  return r;
}
__device__ __forceinline__ ux4 ld_sc01(const u32* p) {   // L3 fallback (safety)
  ux4 r;
  asm volatile("global_load_dwordx4 %0, %1, off sc0 sc1\n\ts_waitcnt vmcnt(0)"
               : "=v"(r) : "v"(p) : "memory");
  return r;
}
__device__ __forceinline__ u32 fp8pack4(ux4 v) {   // 4 bf16 (hi halves) -> 4 fp8
  __hip_fp8_e4m3 q0(bf2f((unsigned short)(v.x >> 16)));
  __hip_fp8_e4m3 q1(bf2f((unsigned short)(v.y >> 16)));
  __hip_fp8_e4m3 q2(bf2f((unsigned short)(v.z >> 16)));
  __hip_fp8_e4m3 q3(bf2f((unsigned short)(v.w >> 16)));
  return (u32)q0.__x | ((u32)q1.__x << 8) | ((u32)q2.__x << 16) | ((u32)q3.__x << 24);
}

// -------- persistent recurrence: batch-per-XCD, fp8 weights fully LDS-resident ------
__global__ void __launch_bounds__(256, 1)
recur(const unsigned char* __restrict__ gf8, const unsigned char* __restrict__ wg8,
      const __hip_bfloat16* __restrict__ XG, const float* __restrict__ beg,
      u32* h_tag, u32* g_tag, int* teamcnt, float* d_out) {
  __shared__ unsigned char gw8[131072];      // 128 KB gate B-frags (fp8, x16)
  __shared__ unsigned char hstage8[1024];    // h vector, fp8
  __shared__ unsigned char gstage8[1024];    // g vector, fp8
  __shared__ float act_lds[128];             // phase-A D row0 per gate
  __shared__ float exk[128];                 // phase-B K-split partials
  __shared__ unsigned short xg_lds[2][128];  // XG slice dbuf [gate*32+col]
  __shared__ int sh_xid, sh_jb;

  const int tid = threadIdx.x;
  const int w = tid >> 6, lane = tid & 63, rgrp = lane >> 4;

  // rendezvous: team = physical XCD, role jb = claim order within team
  if (tid == 0) {
    u32 xid;
    asm volatile("s_getreg_b32 %0, hwreg(HW_REG_XCC_ID)" : "=s"(xid));
    sh_xid = (int)(xid & 7u);
    sh_jb = atomicAdd(&teamcnt[xid & 7u], 1) & 31;
  }
  __syncthreads();
  const int b = sh_xid, jb = sh_jb;          // batch b, owns h-cols [jb*32, jb*32+32)

  // copy this block's 128 KB fp8 gate-weight fragments into LDS (one-time)
  {
    const ux4* src = reinterpret_cast<const ux4*>(gf8 + (size_t)jb*131072);
    ux4* dst = reinterpret_cast<ux4*>(gw8);
    for (int i = tid; i < 8192; i += 256) dst[i] = src[i];
  }
  // Weg fp8 fragments -> VGPR (16 u64 = 32 VGPRs; small enough to stay resident)
  u64 wegr[16];
#pragma unroll
  for (int q = 0; q < 8; ++q)
#pragma unroll
    for (int ct = 0; ct < 2; ++ct)
      wegr[q*2 + ct] = *reinterpret_cast<const u64*>(
          wg8 + (size_t)jb*32768 + (((w*8 + q)*2 + ct)*512) + lane*8);

  float begv = 0.f, c_st = 0.f, n_st = 0.f;
  float i_v = 0.f, f_v = 0.f, o_v = 0.f, c_new = 0.f;
  if (tid < 32) begv = beg[jb*32 + tid];
  if (tid < 32) {  // stage XG[0]  (layout gate*32+col)
    int gate = tid >> 3, ch = tid & 7;
    u64 v = *reinterpret_cast<const u64*>(
        &XG[((size_t)b)*4096 + gate*1024 + jb*32 + ch*4]);
    reinterpret_cast<u64*>(&xg_lds[0][0])[tid] = v;
  }
  __syncthreads();

#pragma unroll 1
  for (int t = 0; t < S_LEN; ++t) {
    // issue next-step XG loads early (hidden under poll)
    u64 xgv = 0;
    const int q32 = tid - 192;
    if (q32 >= 0 && q32 < 32 && t < S_LEN - 1) {
      int gate = q32 >> 3, ch = q32 & 7;
      xgv = *reinterpret_cast<const u64*>(
          &XG[((size_t)(t+1)*8 + b)*4096 + gate*1024 + jb*32 + ch*4]);
    }
    // ---- poll h (tag t), stage as fp8 ----
    {
      const u32* hp = h_tag + b*1024 + tid*4;
      u32 et = (u32)t; ux4 v; int rnd = 0;
      while (true) {
        v = ((++rnd) & 3) ? ld_sc0(hp) : ld_sc01(hp);
        if (!(((v.x ^ et) | (v.y ^ et) | (v.z ^ et) | (v.w ^ et)) & 0xffffu)) break;
      }
      *reinterpret_cast<u32*>(&hstage8[tid*4]) = fp8pack4(v);
    }
    __syncthreads();                         // B1: hstage ready
    if (q32 >= 0 && q32 < 32 && t < S_LEN - 1)   // land XG prefetch
      reinterpret_cast<u64*>(&xg_lds[(t+1) & 1][0])[q32] = xgv;
    // ---- phase A: wave w -> gate w, 32 cols, K=1024 (fp8 MFMA, all from LDS) ----
    fx4 a00 = {0,0,0,0}, a01 = {0,0,0,0}, a10 = {0,0,0,0}, a11 = {0,0,0,0};
#pragma unroll
    for (int k32 = 0; k32 < 32; ++k32) {
      u64 av = *reinterpret_cast<const u64*>(&hstage8[k32*32 + rgrp*8]);
      u64 b0 = *reinterpret_cast<const u64*>(&gw8[(((w*2 + 0)*32 + k32)*512) + lane*8]);
      u64 b1 = *reinterpret_cast<const u64*>(&gw8[(((w*2 + 1)*32 + k32)*512) + lane*8]);
      if (k32 & 1) {
        a10 = __builtin_amdgcn_mfma_f32_16x16x32_fp8_fp8((long long)av, (long long)b0, a10, 0, 0, 0);
        a11 = __builtin_amdgcn_mfma_f32_16x16x32_fp8_fp8((long long)av, (long long)b1, a11, 0, 0, 0);
      } else {
        a00 = __builtin_amdgcn_mfma_f32_16x16x32_fp8_fp8((long long)av, (long long)b0, a00, 0, 0, 0);
        a01 = __builtin_amdgcn_mfma_f32_16x16x32_fp8_fp8((long long)av, (long long)b1, a01, 0, 0, 0);
      }
    }
    if (lane < 16) {                          // D row 0 = lanes 0-15, reg 0
      act_lds[w*32 + lane]      = a00[0] + a10[0];
      act_lds[w*32 + 16 + lane] = a01[0] + a11[0];
    }
    __syncthreads();                         // B2: preacts ready
    if (tid < 32) {   // gates + c-state; publish g ASAP (1/16 un-scale)
      int c = tid;
      const unsigned short* xga = &xg_lds[t & 1][0];
      float pg = act_lds[64 + c]*0.0625f + bf2f(xga[64 + c]);
      float g_v = tanhf(pg);
      __hip_atomic_store(&g_tag[b*1024 + jb*32 + c],
                         ((u32)f2bf(g_v) << 16) | (u32)(t + 1),
                         __ATOMIC_RELAXED, __HIP_MEMORY_SCOPE_AGENT);
      float pi = act_lds[c]*0.0625f      + bf2f(xga[c]);
      float pf = act_lds[32 + c]*0.0625f + bf2f(xga[32 + c]);
      float po = act_lds[96 + c]*0.0625f + bf2f(xga[96 + c]);
      i_v = 1.f / (1.f + expf(-pi));
      f_v = 1.f / (1.f + expf(-pf));
      o_v = 1.f / (1.f + expf(-po));
      c_new = f_v * c_st + i_v * g_v; c_st = c_new;
    }
    // ---- poll g (tag t+1), stage as fp8 ----
    {
      const u32* gp = g_tag + b*1024 + tid*4;
      u32 et = (u32)(t + 1); ux4 v; int rnd = 0;
      while (true) {
        v = ((++rnd) & 3) ? ld_sc0(gp) : ld_sc01(gp);
        if (!(((v.x ^ et) | (v.y ^ et) | (v.z ^ et) | (v.w ^ et)) & 0xffffu)) break;
      }
      *reinterpret_cast<u32*>(&gstage8[tid*4]) = fp8pack4(v);
    }
    __syncthreads();                         // B3: gstage ready
    // ---- phase B: e = g @ Weg, K split across 4 waves (fp8) ----
    fx4 e00 = {0,0,0,0}, e01 = {0,0,0,0}, e10 = {0,0,0,0}, e11 = {0,0,0,0};
#pragma unroll
    for (int q = 0; q < 8; ++q) {
      u64 av = *reinterpret_cast<const u64*>(&gstage8[w*256 + q*32 + rgrp*8]);
      if (q & 1) {
        e10 = __builtin_amdgcn_mfma_f32_16x16x32_fp8_fp8((long long)av, (long long)wegr[q*2],     e10, 0, 0, 0);
        e11 = __builtin_amdgcn_mfma_f32_16x16x32_fp8_fp8((long long)av, (long long)wegr[q*2 + 1], e11, 0, 0, 0);
      } else {
        e00 = __builtin_amdgcn_mfma_f32_16x16x32_fp8_fp8((long long)av, (long long)wegr[q*2],     e00, 0, 0, 0);
        e01 = __builtin_amdgcn_mfma_f32_16x16x32_fp8_fp8((long long)av, (long long)wegr[q*2 + 1], e01, 0, 0, 0);
      }
    }
    if (lane < 16) {
      exk[w*32 + lane]      = e00[0] + e10[0];
      exk[w*32 + 16 + lane] = e01[0] + e11[0];
    }
    __syncthreads();                         // B4: exk ready
    if (tid < 32) {
      float s = (exk[tid] + exk[32 + tid] + exk[64 + tid] + exk[96 + tid])*0.0625f + begv;
      float e = expf(s);
      float n_new = f_v * n_st + i_v * e; n_st = n_new;
      float h_new = o_v * (c_new / n_new);
      if (t < S_LEN - 1) {
        __hip_atomic_store(&h_tag[b*1024 + jb*32 + tid],
                           ((u32)f2bf(h_new) << 16) | (u32)(t + 1),
                           __ATOMIC_RELAXED, __HIP_MEMORY_SCOPE_AGENT);
      }
      d_out[((size_t)b*2048 + t)*1024 + jb*32 + tid] = h_new;   // h history (pre-LN)
      if (t == S_LEN - 1) {
        d_out[OUTBASE +         (size_t)b*1024 + jb*32 + tid] = h_new;  // h_f
        d_out[OUTBASE +  8192 + (size_t)b*1024 + jb*32 + tid] = c_new;  // c_f
        d_out[OUTBASE + 16384 + (size_t)b*1024 + jb*32 + tid] = n_new;  // n_f
      }
    }
  }
}

// ---------------- residual + LayerNorm (in-place on d_out) ----------------
__global__ __launch_bounds__(256) void ln_k(const float* __restrict__ x,
                                            const float* __restrict__ gamma,
                                            const float* __restrict__ beta,
                                            float* __restrict__ out) {
  const int r = blockIdx.x, tid = threadIdx.x;
  float* orow = out + (size_t)r * 1024;
  const float* xrow = x + (size_t)r * 1024;
  fx4 h4 = *reinterpret_cast<const fx4*>(orow + tid*4);
  fx4 x4 = *reinterpret_cast<const fx4*>(xrow + tid*4);
  fx4 y = h4 + x4;
  float s = y[0] + y[1] + y[2] + y[3];
  float s2 = y[0]*y[0] + y[1]*y[1] + y[2]*y[2] + y[3]*y[3];
#pragma unroll
  for (int m = 1; m < 64; m <<= 1) { s += __shfl_xor(s, m, 64); s2 += __shfl_xor(s2, m, 64); }
  __shared__ float ps[4], ps2[4], stats[2];
  if ((tid & 63) == 0) { ps[tid >> 6] = s; ps2[tid >> 6] = s2; }
  __syncthreads();
  if (tid == 0) {
    float t1 = ps[0] + ps[1] + ps[2] + ps[3];
    float t2 = ps2[0] + ps2[1] + ps2[2] + ps2[3];
    float mu = t1 * (1.f / 1024.f);
    float var = t2 * (1.f / 1024.f) - mu * mu;
    stats[0] = mu; stats[1] = rsqrtf(var + 1e-5f);
  }
  __syncthreads();
  float mu = stats[0], rs = stats[1];
  fx4 g4 = *reinterpret_cast<const fx4*>(gamma + tid*4);
  fx4 b4 = *reinterpret_cast<const fx4*>(beta + tid*4);
  fx4 o4;
#pragma unroll
  for (int u = 0; u < 4; ++u) o4[u] = (y[u] - mu) * rs * g4[u] + b4[u];
  *reinterpret_cast<fx4*>(orow + tid*4) = o4;
}

extern "C" void kernel_launch(void* const* d_in, const int* in_sizes, int n_in,
                              void* d_out, int out_size, void* d_ws, size_t ws_size,
                              hipStream_t stream) {
  const float* x    = (const float*)d_in[0];
  const float* Wi   = (const float*)d_in[1];
  const float* bi   = (const float*)d_in[2];
  const float* Wf   = (const float*)d_in[3];
  const float* bfv  = (const float*)d_in[4];
  const float* Wg   = (const float*)d_in[5];
  const float* bg   = (const float*)d_in[6];
  const float* Wo   = (const float*)d_in[7];
  const float* bo   = (const float*)d_in[8];
  const float* Weg  = (const float*)d_in[9];
  const float* beg  = (const float*)d_in[10];
  const float* gamma= (const float*)d_in[11];
  const float* beta = (const float*)d_in[12];
  float* out = (float*)d_out;
  char* ws = (char*)d_ws;

  __hip_bfloat16* XG   = (__hip_bfloat16*)(ws);                    // 134217728 B
  __hip_bfloat16* xbf  = (__hip_bfloat16*)(ws + 134217728ull);     //  33554432 B
  __hip_bfloat16* WxT  = (__hip_bfloat16*)(ws + 167772160ull);     //   8388608 B
  unsigned char* gf8   = (unsigned char*)(ws + 176160768ull);      //   4194304 B
  unsigned char* wg8   = (unsigned char*)(ws + 184549376ull);      //   1048576 B
  float* bcat          = (float*)(ws + 186646528ull);              //     16384 B
  u32* h_tag           = (u32*)(ws + 186662912ull);                //     32768 B
  u32* g_tag           = (u32*)(ws + 186695680ull);                //     32768 B
  int* teamcnt         = (int*)(ws + 186728448ull);                //       128 B

  prep_w<<<dim3(32, 32, 4), dim3(32, 8), 0, stream>>>(Wi, Wf, Wg, Wo, WxT);
  prep_gfrag8<<<dim3(4096), dim3(128), 0, stream>>>(Wi, Wf, Wg, Wo, gf8);
  prep_wegfrag8<<<dim3(1024), dim3(128), 0, stream>>>(Weg, wg8);
  init_k<<<dim3(64), dim3(256), 0, stream>>>(h_tag, g_tag, teamcnt, bi, bfv, bg, bo, bcat);
  conv_x<<<dim3(8192), dim3(256), 0, stream>>>(x, xbf);
  gemm_x<<<dim3(32, 128), dim3(256), 0, stream>>>(xbf, WxT, bcat, XG);
  recur<<<dim3(256), dim3(256), 0, stream>>>(gf8, wg8, XG, beg, h_tag, g_tag, teamcnt, out);
  ln_k<<<dim3(16384), dim3(256), 0, stream>>>(x, gamma, beta, out);
}